// Round 1
// baseline (482.812 us; speedup 1.0000x reference)
//
#include <hip/hip_runtime.h>

#define NIMG 16
#define H 512
#define W 512
#define CH 256
#define CW 256
#define HALF 7   // PATCH=15

// ---------------------------------------------------------------------------
// K1: per 2x2 pixel block, compute dY (full res) and pooled dU, dV.
// idx = n*CH*CW + cy*CW + cx ; total = 16*256*256 = 1,048,576
// ---------------------------------------------------------------------------
__global__ void diff_kernel(const float* __restrict__ in, const float* __restrict__ tgt,
                            float* __restrict__ dY, float* __restrict__ dU,
                            float* __restrict__ dV) {
    int idx = blockIdx.x * 256 + threadIdx.x;
    int cx = idx & (CW - 1);
    int cy = (idx >> 8) & (CH - 1);
    int n  = idx >> 16;
    if (n >= NIMG) return;

    const size_t plane = (size_t)H * W;
    const float* pi = in  + (size_t)n * 3 * plane;
    const float* pt = tgt + (size_t)n * 3 * plane;

    int y0 = cy << 1, x0 = cx << 1;
    size_t o0 = (size_t)y0 * W + x0;
    size_t o1 = o0 + W;

    float2 ir0 = *(const float2*)(pi + o0);
    float2 ir1 = *(const float2*)(pi + o1);
    float2 ig0 = *(const float2*)(pi + plane + o0);
    float2 ig1 = *(const float2*)(pi + plane + o1);
    float2 ib0 = *(const float2*)(pi + 2 * plane + o0);
    float2 ib1 = *(const float2*)(pi + 2 * plane + o1);

    float2 tr0 = *(const float2*)(pt + o0);
    float2 tr1 = *(const float2*)(pt + o1);
    float2 tg0 = *(const float2*)(pt + plane + o0);
    float2 tg1 = *(const float2*)(pt + plane + o1);
    float2 tb0 = *(const float2*)(pt + 2 * plane + o0);
    float2 tb1 = *(const float2*)(pt + 2 * plane + o1);

    float dr00 = ir0.x - tr0.x, dr01 = ir0.y - tr0.y;
    float dr10 = ir1.x - tr1.x, dr11 = ir1.y - tr1.y;
    float dg00 = ig0.x - tg0.x, dg01 = ig0.y - tg0.y;
    float dg10 = ig1.x - tg1.x, dg11 = ig1.y - tg1.y;
    float db00 = ib0.x - tb0.x, db01 = ib0.y - tb0.y;
    float db10 = ib1.x - tb1.x, db11 = ib1.y - tb1.y;

    // Y = 0.299 r + 0.587 g + 0.114 b
    float2 y0v, y1v;
    y0v.x = 0.299f * dr00 + 0.587f * dg00 + 0.114f * db00;
    y0v.y = 0.299f * dr01 + 0.587f * dg01 + 0.114f * db01;
    y1v.x = 0.299f * dr10 + 0.587f * dg10 + 0.114f * db10;
    y1v.y = 0.299f * dr11 + 0.587f * dg11 + 0.114f * db11;

    float* dYp = dY + (size_t)n * plane;
    *(float2*)(dYp + o0) = y0v;
    *(float2*)(dYp + o1) = y1v;

    float sr = dr00 + dr01 + dr10 + dr11;
    float sg = dg00 + dg01 + dg10 + dg11;
    float sb = db00 + db01 + db10 + db11;

    // U = -0.169 r - 0.331 g + 0.5 b (+128 cancels); V = 0.5 r - 0.46 g - 0.04 b
    dU[idx] = (-0.169f * sr - 0.331f * sg + 0.5f * sb) * 0.25f;
    dV[idx] = ( 0.5f   * sr - 0.46f  * sg - 0.04f * sb) * 0.25f;
}

// ---------------------------------------------------------------------------
// K2: horizontal 15-tap box sum (zero pad == clamp loop bounds), per element.
// w is a power of two; wMask = w-1.
// ---------------------------------------------------------------------------
__global__ void hbox_kernel(const float* __restrict__ src, float* __restrict__ dst,
                            int wMask, int total) {
    int idx = blockIdx.x * 256 + threadIdx.x;
    if (idx >= total) return;
    int x = idx & wMask;
    int xa = max(x - HALF, 0);
    int xb = min(x + HALF, wMask);
    const float* row = src + (idx - x);
    float s = 0.f;
    for (int xx = xa; xx <= xb; ++xx) s += row[xx];
    dst[idx] = s;
}

// ---------------------------------------------------------------------------
// K3: vertical 15-tap box sum, square, block-reduce, atomicAdd(out, sum/cnt).
// ---------------------------------------------------------------------------
__global__ void vbox_sq_reduce_kernel(const float* __restrict__ src, int wShift,
                                      int hMask, float invCount,
                                      float* __restrict__ out, int total) {
    int idx = blockIdx.x * 256 + threadIdx.x;
    float val = 0.0f;
    if (idx < total) {
        int x_and_base = idx - (((idx >> wShift) & hMask) << wShift); // n*h*w + x
        int y  = (idx >> wShift) & hMask;
        int ya = max(y - HALF, 0);
        int yb = min(y + HALF, hMask);
        const float* col = src + x_and_base;
        float s = 0.f;
        for (int yy = ya; yy <= yb; ++yy) s += col[(size_t)yy << wShift];
        val = s * s;
    }
    // wave64 reduce
    for (int o = 32; o > 0; o >>= 1) val += __shfl_down(val, o, 64);
    __shared__ float partial[4];
    int lane = threadIdx.x & 63, wid = threadIdx.x >> 6;
    if (lane == 0) partial[wid] = val;
    __syncthreads();
    if (threadIdx.x == 0) {
        float t = partial[0] + partial[1] + partial[2] + partial[3];
        atomicAdd(out, t * invCount);
    }
}

extern "C" void kernel_launch(void* const* d_in, const int* in_sizes, int n_in,
                              void* d_out, int out_size, void* d_ws, size_t ws_size,
                              hipStream_t stream) {
    const float* input  = (const float*)d_in[0];
    const float* target = (const float*)d_in[1];
    float* out = (float*)d_out;

    const size_t yElems = (size_t)NIMG * H * W;      // 4,194,304
    const size_t cElems = (size_t)NIMG * CH * CW;    // 1,048,576

    float* ws = (float*)d_ws;
    float* dY = ws;                 // yElems
    float* dU = dY + yElems;        // cElems
    float* dV = dU + cElems;        // cElems
    float* hY = dV + cElems;        // yElems
    float* hU = hY + yElems;        // cElems
    float* hV = hU + cElems;        // cElems
    // total 12,582,912 floats = ~50.3 MB

    hipMemsetAsync(out, 0, sizeof(float), stream);

    diff_kernel<<<(int)(cElems / 256), 256, 0, stream>>>(input, target, dY, dU, dV);

    hbox_kernel<<<(int)(yElems / 256), 256, 0, stream>>>(dY, hY, W - 1, (int)yElems);
    hbox_kernel<<<(int)(cElems / 256), 256, 0, stream>>>(dU, hU, CW - 1, (int)cElems);
    hbox_kernel<<<(int)(cElems / 256), 256, 0, stream>>>(dV, hV, CW - 1, (int)cElems);

    vbox_sq_reduce_kernel<<<(int)(yElems / 256), 256, 0, stream>>>(
        hY, 9, H - 1, 1.0f / (float)yElems, out, (int)yElems);
    vbox_sq_reduce_kernel<<<(int)(cElems / 256), 256, 0, stream>>>(
        hU, 8, CH - 1, 1.0f / (float)cElems, out, (int)cElems);
    vbox_sq_reduce_kernel<<<(int)(cElems / 256), 256, 0, stream>>>(
        hV, 8, CH - 1, 1.0f / (float)cElems, out, (int)cElems);
}

// Round 2
// 177.970 us; speedup vs baseline: 2.7129x; 2.7129x over previous
//
#include <hip/hip_runtime.h>

#define NIMG 16
#define H 512
#define W 512
#define CH 256
#define CW 256
#define HALF 7   // PATCH=15

// ---------------------------------------------------------------------------
// K1: per 2x2 pixel block, compute dY (full res) and pooled dU, dV.
// idx = n*CH*CW + cy*CW + cx ; total = 16*256*256 = 1,048,576
// ---------------------------------------------------------------------------
__global__ void diff_kernel(const float* __restrict__ in, const float* __restrict__ tgt,
                            float* __restrict__ dY, float* __restrict__ dU,
                            float* __restrict__ dV) {
    int idx = blockIdx.x * 256 + threadIdx.x;
    int cx = idx & (CW - 1);
    int cy = (idx >> 8) & (CH - 1);
    int n  = idx >> 16;

    const size_t plane = (size_t)H * W;
    const float* pi = in  + (size_t)n * 3 * plane;
    const float* pt = tgt + (size_t)n * 3 * plane;

    int y0 = cy << 1, x0 = cx << 1;
    size_t o0 = (size_t)y0 * W + x0;
    size_t o1 = o0 + W;

    float2 ir0 = *(const float2*)(pi + o0);
    float2 ir1 = *(const float2*)(pi + o1);
    float2 ig0 = *(const float2*)(pi + plane + o0);
    float2 ig1 = *(const float2*)(pi + plane + o1);
    float2 ib0 = *(const float2*)(pi + 2 * plane + o0);
    float2 ib1 = *(const float2*)(pi + 2 * plane + o1);

    float2 tr0 = *(const float2*)(pt + o0);
    float2 tr1 = *(const float2*)(pt + o1);
    float2 tg0 = *(const float2*)(pt + plane + o0);
    float2 tg1 = *(const float2*)(pt + plane + o1);
    float2 tb0 = *(const float2*)(pt + 2 * plane + o0);
    float2 tb1 = *(const float2*)(pt + 2 * plane + o1);

    float dr00 = ir0.x - tr0.x, dr01 = ir0.y - tr0.y;
    float dr10 = ir1.x - tr1.x, dr11 = ir1.y - tr1.y;
    float dg00 = ig0.x - tg0.x, dg01 = ig0.y - tg0.y;
    float dg10 = ig1.x - tg1.x, dg11 = ig1.y - tg1.y;
    float db00 = ib0.x - tb0.x, db01 = ib0.y - tb0.y;
    float db10 = ib1.x - tb1.x, db11 = ib1.y - tb1.y;

    float2 y0v, y1v;
    y0v.x = 0.299f * dr00 + 0.587f * dg00 + 0.114f * db00;
    y0v.y = 0.299f * dr01 + 0.587f * dg01 + 0.114f * db01;
    y1v.x = 0.299f * dr10 + 0.587f * dg10 + 0.114f * db10;
    y1v.y = 0.299f * dr11 + 0.587f * dg11 + 0.114f * db11;

    float* dYp = dY + (size_t)n * plane;
    *(float2*)(dYp + o0) = y0v;
    *(float2*)(dYp + o1) = y1v;

    float sr = dr00 + dr01 + dr10 + dr11;
    float sg = dg00 + dg01 + dg10 + dg11;
    float sb = db00 + db01 + db10 + db11;

    dU[idx] = (-0.169f * sr - 0.331f * sg + 0.5f * sb) * 0.25f;
    dV[idx] = ( 0.5f   * sr - 0.46f  * sg - 0.04f * sb) * 0.25f;
}

// ---------------------------------------------------------------------------
// K2: horizontal 15-tap box sum, fully unrolled with clamp+select (zero pad).
// ---------------------------------------------------------------------------
__global__ void hbox_kernel(const float* __restrict__ src, float* __restrict__ dst,
                            int wMask) {
    int idx = blockIdx.x * 256 + threadIdx.x;
    int x = idx & wMask;
    const float* row = src + (idx - x);
    float s = 0.f;
#pragma unroll
    for (int t = -HALF; t <= HALF; ++t) {
        int xx = x + t;
        int xc = min(max(xx, 0), wMask);
        float v = row[xc];
        s += (xx == xc) ? v : 0.f;
    }
    dst[idx] = s;
}

// ---------------------------------------------------------------------------
// K3: vertical 15-tap box sum, square, block-reduce, write partial (scaled).
// No atomics: partials[partOff + blockIdx.x] = block_sum * invCount.
// ---------------------------------------------------------------------------
__global__ void vbox_sq_partial_kernel(const float* __restrict__ src, int wShift,
                                       int hMask, float invCount,
                                       float* __restrict__ partials, int partOff) {
    int idx = blockIdx.x * 256 + threadIdx.x;
    int y = (idx >> wShift) & hMask;
    const float* col = src + (idx - (y << wShift));  // base + x (within image n)
    float s = 0.f;
#pragma unroll
    for (int t = -HALF; t <= HALF; ++t) {
        int yy = y + t;
        int yc = min(max(yy, 0), hMask);
        float v = col[(size_t)yc << wShift];
        s += (yy == yc) ? v : 0.f;
    }
    float val = s * s;

    for (int o = 32; o > 0; o >>= 1) val += __shfl_down(val, o, 64);
    __shared__ float partial[4];
    int lane = threadIdx.x & 63, wid = threadIdx.x >> 6;
    if (lane == 0) partial[wid] = val;
    __syncthreads();
    if (threadIdx.x == 0) {
        float t = partial[0] + partial[1] + partial[2] + partial[3];
        partials[partOff + blockIdx.x] = t * invCount;
    }
}

// ---------------------------------------------------------------------------
// K4: single-block final sum of all partials -> out[0].
// ---------------------------------------------------------------------------
__global__ void final_reduce_kernel(const float* __restrict__ partials, int n,
                                    float* __restrict__ out) {
    float s = 0.f;
    for (int i = threadIdx.x; i < n; i += 1024) s += partials[i];
    for (int o = 32; o > 0; o >>= 1) s += __shfl_down(s, o, 64);
    __shared__ float partial[16];
    int lane = threadIdx.x & 63, wid = threadIdx.x >> 6;
    if (lane == 0) partial[wid] = s;
    __syncthreads();
    if (threadIdx.x == 0) {
        float t = 0.f;
#pragma unroll
        for (int i = 0; i < 16; ++i) t += partial[i];
        *out = t;
    }
}

extern "C" void kernel_launch(void* const* d_in, const int* in_sizes, int n_in,
                              void* d_out, int out_size, void* d_ws, size_t ws_size,
                              hipStream_t stream) {
    const float* input  = (const float*)d_in[0];
    const float* target = (const float*)d_in[1];
    float* out = (float*)d_out;

    const size_t yElems = (size_t)NIMG * H * W;      // 4,194,304
    const size_t cElems = (size_t)NIMG * CH * CW;    // 1,048,576

    float* ws = (float*)d_ws;
    float* dY = ws;                 // yElems
    float* dU = dY + yElems;        // cElems
    float* dV = dU + cElems;        // cElems
    float* hY = dV + cElems;        // yElems
    float* hU = hY + yElems;        // cElems
    float* hV = hU + cElems;        // cElems  (hU,hV contiguous)
    // Partials reuse the dU region (dead after the hbox pass). Max 24576 floats.
    float* partials = dU;

    const int gY  = (int)(yElems / 256);      // 16384 blocks
    const int gUV = (int)(2 * cElems / 256);  // 8192 blocks (U and V fused)
    const int nPart = gY + gUV;               // 24576

    diff_kernel<<<(int)(cElems / 256), 256, 0, stream>>>(input, target, dY, dU, dV);

    hbox_kernel<<<gY, 256, 0, stream>>>(dY, hY, W - 1);
    hbox_kernel<<<gUV, 256, 0, stream>>>(dU, hU, CW - 1);  // U and V in one launch

    vbox_sq_partial_kernel<<<gY, 256, 0, stream>>>(
        hY, 9, H - 1, 1.0f / (float)yElems, partials, 0);
    vbox_sq_partial_kernel<<<gUV, 256, 0, stream>>>(
        hU, 8, CH - 1, 1.0f / (float)cElems, partials, gY);

    final_reduce_kernel<<<1, 1024, 0, stream>>>(partials, nPart, out);
}

// Round 3
// 150.029 us; speedup vs baseline: 3.2181x; 1.1862x over previous
//
#include <hip/hip_runtime.h>

#define NIMG 16
#define H 512
#define W 512
#define CH 256
#define CW 256
#define HALF 7   // PATCH=15

// ---------------------------------------------------------------------------
// K1: fused diff + horizontal 15-tap box. One block (256 thr) per (n, cy)
// full-res row pair. dY rows + pooled dU/dV row live only in LDS (zero-padded
// +-8 so hbox needs no clamping). Outputs hY (16 MB) and hUV (8 MB).
// hUV plane index p = 2n+uv, each plane 256x256 contiguous.
// ---------------------------------------------------------------------------
__global__ void diff_hbox_kernel(const float* __restrict__ in, const float* __restrict__ tgt,
                                 float* __restrict__ hY, float* __restrict__ hUV) {
    __shared__ float sY0[W + 16], sY1[W + 16], sU[CW + 16], sV[CW + 16];
    const int tid = threadIdx.x;
    const int cy = blockIdx.x & (CH - 1);
    const int n  = blockIdx.x >> 8;

    if (tid < 8) {
        sY0[tid] = 0.f; sY0[W + 8 + tid] = 0.f;
        sY1[tid] = 0.f; sY1[W + 8 + tid] = 0.f;
        sU[tid] = 0.f;  sU[CW + 8 + tid] = 0.f;
        sV[tid] = 0.f;  sV[CW + 8 + tid] = 0.f;
    }

    const size_t plane = (size_t)H * W;
    const float* pi = in  + (size_t)n * 3 * plane;
    const float* pt = tgt + (size_t)n * 3 * plane;

    const int y0 = cy << 1;
    const int x0 = tid << 1;
    const size_t o0 = (size_t)y0 * W + x0;
    const size_t o1 = o0 + W;

    float2 ir0 = *(const float2*)(pi + o0);
    float2 ir1 = *(const float2*)(pi + o1);
    float2 ig0 = *(const float2*)(pi + plane + o0);
    float2 ig1 = *(const float2*)(pi + plane + o1);
    float2 ib0 = *(const float2*)(pi + 2 * plane + o0);
    float2 ib1 = *(const float2*)(pi + 2 * plane + o1);

    float2 tr0 = *(const float2*)(pt + o0);
    float2 tr1 = *(const float2*)(pt + o1);
    float2 tg0 = *(const float2*)(pt + plane + o0);
    float2 tg1 = *(const float2*)(pt + plane + o1);
    float2 tb0 = *(const float2*)(pt + 2 * plane + o0);
    float2 tb1 = *(const float2*)(pt + 2 * plane + o1);

    float dr00 = ir0.x - tr0.x, dr01 = ir0.y - tr0.y;
    float dr10 = ir1.x - tr1.x, dr11 = ir1.y - tr1.y;
    float dg00 = ig0.x - tg0.x, dg01 = ig0.y - tg0.y;
    float dg10 = ig1.x - tg1.x, dg11 = ig1.y - tg1.y;
    float db00 = ib0.x - tb0.x, db01 = ib0.y - tb0.y;
    float db10 = ib1.x - tb1.x, db11 = ib1.y - tb1.y;

    sY0[8 + x0]     = 0.299f * dr00 + 0.587f * dg00 + 0.114f * db00;
    sY0[8 + x0 + 1] = 0.299f * dr01 + 0.587f * dg01 + 0.114f * db01;
    sY1[8 + x0]     = 0.299f * dr10 + 0.587f * dg10 + 0.114f * db10;
    sY1[8 + x0 + 1] = 0.299f * dr11 + 0.587f * dg11 + 0.114f * db11;

    float sr = dr00 + dr01 + dr10 + dr11;
    float sg = dg00 + dg01 + dg10 + dg11;
    float sb = db00 + db01 + db10 + db11;
    sU[8 + tid] = (-0.169f * sr - 0.331f * sg + 0.5f * sb) * 0.25f;
    sV[8 + tid] = ( 0.5f   * sr - 0.46f  * sg - 0.04f * sb) * 0.25f;

    __syncthreads();

    // --- hbox Y: each thread 4 consecutive outputs in one row (running sum) ---
    {
        const int row = tid >> 7;              // 0 or 1
        const int xb  = (tid & 127) << 2;      // 0..508
        const float* srow = row ? sY1 : sY0;
        float s = 0.f;
#pragma unroll
        for (int j = 1; j <= 15; ++j) s += srow[xb + j];   // x in [xb-7, xb+7]
        float4 o;
        o.x = s; s += srow[xb + 16] - srow[xb + 1];
        o.y = s; s += srow[xb + 17] - srow[xb + 2];
        o.z = s; s += srow[xb + 18] - srow[xb + 3];
        o.w = s;
        *(float4*)(hY + ((size_t)n * H + y0 + row) * W + xb) = o;
    }

    // --- hbox chroma: threads 0-127 -> U, 128-255 -> V, 2 outputs each ---
    {
        const int uv = tid >> 7;
        const int t  = tid & 127;
        const int xb = t << 1;                 // 0..254
        const float* srow = uv ? sV : sU;
        float s = 0.f;
#pragma unroll
        for (int j = 1; j <= 15; ++j) s += srow[xb + j];
        float2 o;
        o.x = s; s += srow[xb + 16] - srow[xb + 1];
        o.y = s;
        const size_t p = (size_t)(n * 2 + uv);
        *(float2*)(hUV + (p * CH + cy) * CW + xb) = o;
    }
}

// ---------------------------------------------------------------------------
// K2: vertical 15-tap box + square + block partial, Y and UV in one launch.
// ---------------------------------------------------------------------------
__global__ void vbox_sq_partial_kernel(const float* __restrict__ hY,
                                       const float* __restrict__ hUV,
                                       int gY, float invY, float invC,
                                       float* __restrict__ partials) {
    const int b = blockIdx.x;
    const float* src; int wShift, hMask; float inv; int idx;
    if (b < gY) {
        src = hY; wShift = 9; hMask = H - 1; inv = invY;
        idx = b * 256 + threadIdx.x;
    } else {
        src = hUV; wShift = 8; hMask = CH - 1; inv = invC;
        idx = (b - gY) * 256 + threadIdx.x;
    }
    const int y = (idx >> wShift) & hMask;
    const float* col = src + (idx - (y << wShift));
    float s = 0.f;
#pragma unroll
    for (int t = -HALF; t <= HALF; ++t) {
        int yy = y + t;
        int yc = min(max(yy, 0), hMask);
        float v = col[(size_t)yc << wShift];
        s += (yy == yc) ? v : 0.f;
    }
    float val = s * s;

    for (int o = 32; o > 0; o >>= 1) val += __shfl_down(val, o, 64);
    __shared__ float partial[4];
    const int lane = threadIdx.x & 63, wid = threadIdx.x >> 6;
    if (lane == 0) partial[wid] = val;
    __syncthreads();
    if (threadIdx.x == 0) {
        float t = partial[0] + partial[1] + partial[2] + partial[3];
        partials[b] = t * inv;
    }
}

// ---------------------------------------------------------------------------
// K3: single-block final sum of all partials -> out[0].
// ---------------------------------------------------------------------------
__global__ void final_reduce_kernel(const float* __restrict__ partials, int n,
                                    float* __restrict__ out) {
    float s = 0.f;
    for (int i = threadIdx.x; i < n; i += 1024) s += partials[i];
    for (int o = 32; o > 0; o >>= 1) s += __shfl_down(s, o, 64);
    __shared__ float partial[16];
    const int lane = threadIdx.x & 63, wid = threadIdx.x >> 6;
    if (lane == 0) partial[wid] = s;
    __syncthreads();
    if (threadIdx.x == 0) {
        float t = 0.f;
#pragma unroll
        for (int i = 0; i < 16; ++i) t += partial[i];
        *out = t;
    }
}

extern "C" void kernel_launch(void* const* d_in, const int* in_sizes, int n_in,
                              void* d_out, int out_size, void* d_ws, size_t ws_size,
                              hipStream_t stream) {
    const float* input  = (const float*)d_in[0];
    const float* target = (const float*)d_in[1];
    float* out = (float*)d_out;

    const size_t yElems = (size_t)NIMG * H * W;      // 4,194,304
    const size_t cElems = (size_t)NIMG * CH * CW;    // 1,048,576

    float* ws = (float*)d_ws;
    float* hY       = ws;                    // yElems
    float* hUV      = hY + yElems;           // 2*cElems
    float* partials = hUV + 2 * cElems;      // 24576

    const int gY  = (int)(yElems / 256);      // 16384
    const int gUV = (int)(2 * cElems / 256);  // 8192
    const int nPart = gY + gUV;               // 24576

    diff_hbox_kernel<<<NIMG * CH, 256, 0, stream>>>(input, target, hY, hUV);

    vbox_sq_partial_kernel<<<gY + gUV, 256, 0, stream>>>(
        hY, hUV, gY, 1.0f / (float)yElems, 1.0f / (float)cElems, partials);

    final_reduce_kernel<<<1, 1024, 0, stream>>>(partials, nPart, out);
}